// Round 1
// baseline (631.688 us; speedup 1.0000x reference)
//
#include <hip/hip_runtime.h>
#include <math.h>

constexpr int NB = 32;     // batch
constexpr int NL = 512;    // seq len
constexpr int NH = 1024;   // hidden
constexpr int NT = 67;     // tags

// ---------------- wave helpers (wave = 64 on gfx950) ----------------
__device__ __forceinline__ float wave_max_f(float v) {
#pragma unroll
  for (int o = 32; o > 0; o >>= 1) v = fmaxf(v, __shfl_xor(v, o));
  return v;
}
__device__ __forceinline__ float wave_min_f(float v) {
#pragma unroll
  for (int o = 32; o > 0; o >>= 1) v = fminf(v, __shfl_xor(v, o));
  return v;
}
__device__ __forceinline__ float wave_sum_f(float v) {
#pragma unroll
  for (int o = 32; o > 0; o >>= 1) v += __shfl_xor(v, o);
  return v;
}
__device__ __forceinline__ int wave_sum_i(int v) {
#pragma unroll
  for (int o = 32; o > 0; o >>= 1) v += __shfl_xor(v, o);
  return v;
}

// ---------------- K1: scores = log_softmax(leaky_relu(hidden) @ W + b) ----------------
// 256 blocks x 256 threads; 64 rows/block; K staged in chunks of 64.
// Thread (r = tid&63, cg = tid>>6): row r, columns [cg*17, cg*17+17).
// A[64][65]: stride 65 -> bank (r+k)%32, conflict-free lane-over-row reads.
// Wl[64][80]: 4 col-groups of 20 (16B-aligned float4 broadcasts, cg uniform per wave).
constexpr int K1_ROWS = 64, K1_KC = 64;

__global__ __launch_bounds__(256) void k_scores(const float* __restrict__ hidden,
                                                const float* __restrict__ W,
                                                const float* __restrict__ bias,
                                                float* __restrict__ scores) {
  __shared__ float A[K1_ROWS][K1_KC + 1];
  __shared__ float Wl[K1_KC][80];        // reused as Lbuf[64][68] in epilogue
  __shared__ float Pm[K1_ROWS][4];
  __shared__ float Ps[K1_ROWS][4];
  __shared__ float Lse[K1_ROWS];

  const int tid = threadIdx.x;
  const int r = tid & 63;
  const int cg = tid >> 6;
  const size_t r0 = (size_t)blockIdx.x * K1_ROWS;

  float acc[17];
#pragma unroll
  for (int i = 0; i < 17; ++i) acc[i] = 0.f;

  for (int kc = 0; kc < NH; kc += K1_KC) {
    __syncthreads();
    // stage A: 64 rows x 64 k, leaky_relu fused, coalesced float4
#pragma unroll
    for (int rep = 0; rep < 4; ++rep) {
      int idx = rep * 256 + tid;
      int row = idx >> 4, c4 = idx & 15;
      float4 v = *reinterpret_cast<const float4*>(&hidden[(r0 + row) * NH + kc + c4 * 4]);
      v.x = v.x > 0.f ? v.x : 0.01f * v.x;
      v.y = v.y > 0.f ? v.y : 0.01f * v.y;
      v.z = v.z > 0.f ? v.z : 0.01f * v.z;
      v.w = v.w > 0.f ? v.w : 0.01f * v.w;
      A[row][c4 * 4 + 0] = v.x;
      A[row][c4 * 4 + 1] = v.y;
      A[row][c4 * 4 + 2] = v.z;
      A[row][c4 * 4 + 3] = v.w;
    }
    // stage W chunk: 64 x 67, coalesced scalar, group-padded LDS layout
#pragma unroll
    for (int rep = 0; rep < 17; ++rep) {
      int idx = rep * 256 + tid;
      if (idx < K1_KC * NT) {
        int k = idx / NT, t = idx - k * NT;
        Wl[k][(t / 17) * 20 + (t % 17)] = W[(size_t)(kc + k) * NT + t];
      }
    }
    __syncthreads();
    for (int k = 0; k < K1_KC; ++k) {
      float a = A[r][k];
      const float* wr = &Wl[k][cg * 20];
      float4 w0 = *reinterpret_cast<const float4*>(wr);
      float4 w1 = *reinterpret_cast<const float4*>(wr + 4);
      float4 w2 = *reinterpret_cast<const float4*>(wr + 8);
      float4 w3 = *reinterpret_cast<const float4*>(wr + 12);
      float w16 = wr[16];
      acc[0] = fmaf(a, w0.x, acc[0]);
      acc[1] = fmaf(a, w0.y, acc[1]);
      acc[2] = fmaf(a, w0.z, acc[2]);
      acc[3] = fmaf(a, w0.w, acc[3]);
      acc[4] = fmaf(a, w1.x, acc[4]);
      acc[5] = fmaf(a, w1.y, acc[5]);
      acc[6] = fmaf(a, w1.z, acc[6]);
      acc[7] = fmaf(a, w1.w, acc[7]);
      acc[8] = fmaf(a, w2.x, acc[8]);
      acc[9] = fmaf(a, w2.y, acc[9]);
      acc[10] = fmaf(a, w2.z, acc[10]);
      acc[11] = fmaf(a, w2.w, acc[11]);
      acc[12] = fmaf(a, w3.x, acc[12]);
      acc[13] = fmaf(a, w3.y, acc[13]);
      acc[14] = fmaf(a, w3.z, acc[14]);
      acc[15] = fmaf(a, w3.w, acc[15]);
      acc[16] = fmaf(a, w16, acc[16]);
    }
  }
  __syncthreads();  // all waves done reading A/Wl before overlays/epilogue

  const int c0 = cg * 17;
  float pm = -INFINITY;
#pragma unroll
  for (int i = 0; i < 17; ++i) {
    int t = c0 + i;
    if (t < NT) {
      acc[i] += bias[t];
      pm = fmaxf(pm, acc[i]);
    }
  }
  Pm[r][cg] = pm;
  __syncthreads();
  float M = fmaxf(fmaxf(Pm[r][0], Pm[r][1]), fmaxf(Pm[r][2], Pm[r][3]));
  float ps = 0.f;
#pragma unroll
  for (int i = 0; i < 17; ++i) {
    int t = c0 + i;
    if (t < NT) ps += expf(acc[i] - M);
  }
  Ps[r][cg] = ps;
  __syncthreads();
  if (cg == 0) Lse[r] = M + logf(Ps[r][0] + Ps[r][1] + Ps[r][2] + Ps[r][3]);
  __syncthreads();
  float lse = Lse[r];
  float* Lb = &Wl[0][0];  // overlay [64][68]
#pragma unroll
  for (int i = 0; i < 17; ++i) {
    int t = c0 + i;
    if (t < NT) Lb[r * 68 + t] = acc[i] - lse;
  }
  __syncthreads();
  // coalesced store
#pragma unroll
  for (int rep = 0; rep < 17; ++rep) {
    int idx = rep * 256 + tid;
    if (idx < K1_ROWS * NT) {
      int row = idx / NT, t = idx - row * NT;
      scores[(r0 + row) * NT + t] = Lb[row * 68 + t];
    }
  }
}

// ---------------- K2: CRF forward (blocks 0..31) + Viterbi (blocks 32..63) ----------------
// 64 threads = 1 wave per block. Lane l owns tag j=l, plus j2=64+l for l<3.
__global__ __launch_bounds__(64) void k_crf_vit(const float* __restrict__ scores,
                                                const float* __restrict__ trans,
                                                const float* __restrict__ startv,
                                                const float* __restrict__ endv,
                                                const int* __restrict__ labels,
                                                const int* __restrict__ maskp,
                                                float* __restrict__ llh,
                                                float* __restrict__ tags_out) {
  const int lane = threadIdx.x;

  if (blockIdx.x < NB) {
    // ================= CRF log-likelihood for sequence b =================
    const int b = blockIdx.x;
    const float* sc = scores + (size_t)b * NL * NT;
    const int* mk = maskp + b * NL;
    const int* lb = labels + b * NL;
    __shared__ float p_lds[2][68];

    // E = exp(trans) columns for my j's, kept entirely in registers (static unroll).
    const int jc1 = (lane < 3) ? (64 + lane) : 66;  // clamp keeps loads in-bounds
    float ET0[NT], ET1[NT];
#pragma unroll
    for (int i = 0; i < NT; ++i) {
      ET0[i] = __expf(trans[i * NT + lane]);
      ET1[i] = __expf(trans[i * NT + jc1]);
    }
    float a0 = startv[lane] + sc[lane];
    float a1 = (lane < 3) ? (startv[64 + lane] + sc[64 + lane]) : -INFINITY;

    for (int t = 1; t < NL; ++t) {
      float e0 = sc[t * NT + lane];                               // issue loads early
      float e1 = (lane < 3) ? sc[t * NT + 64 + lane] : 0.f;
      int mt = mk[t];
      float aM = a0;
      if (lane < 3) aM = fmaxf(aM, a1);
      float M = wave_max_f(aM);
      int buf = t & 1;
      p_lds[buf][lane] = __expf(a0 - M);
      if (lane < 3) p_lds[buf][64 + lane] = __expf(a1 - M);
      __syncthreads();
      float S0a = 0, S0b = 0, S0c = 0, S0d = 0;
      float S1a = 0, S1b = 0, S1c = 0, S1d = 0;
#pragma unroll
      for (int i4 = 0; i4 < 16; ++i4) {
        float4 pv = *reinterpret_cast<const float4*>(&p_lds[buf][i4 * 4]);
        S0a = fmaf(pv.x, ET0[i4 * 4 + 0], S0a);
        S0b = fmaf(pv.y, ET0[i4 * 4 + 1], S0b);
        S0c = fmaf(pv.z, ET0[i4 * 4 + 2], S0c);
        S0d = fmaf(pv.w, ET0[i4 * 4 + 3], S0d);
        S1a = fmaf(pv.x, ET1[i4 * 4 + 0], S1a);
        S1b = fmaf(pv.y, ET1[i4 * 4 + 1], S1b);
        S1c = fmaf(pv.z, ET1[i4 * 4 + 2], S1c);
        S1d = fmaf(pv.w, ET1[i4 * 4 + 3], S1d);
      }
      {
        float p64 = p_lds[buf][64], p65 = p_lds[buf][65], p66 = p_lds[buf][66];
        S0a = fmaf(p64, ET0[64], S0a);
        S0b = fmaf(p65, ET0[65], S0b);
        S0c = fmaf(p66, ET0[66], S0c);
        S1a = fmaf(p64, ET1[64], S1a);
        S1b = fmaf(p65, ET1[65], S1b);
        S1c = fmaf(p66, ET1[66], S1c);
      }
      float S0 = (S0a + S0b) + (S0c + S0d);
      float S1 = (S1a + S1b) + (S1c + S1d);
      float nxt0 = e0 + M + __logf(S0);
      float nxt1 = e1 + M + __logf(S1);
      if (mt) {
        a0 = nxt0;
        if (lane < 3) a1 = nxt1;
      }
    }
    // denominator = lse(alpha + end)
    float v0 = a0 + endv[lane];
    float v1 = (lane < 3) ? (a1 + endv[64 + lane]) : -INFINITY;
    float M2 = wave_max_f(fmaxf(v0, v1));
    float sd = __expf(v0 - M2) + ((lane < 3) ? __expf(v1 - M2) : 0.f);
    float den = M2 + __logf(wave_sum_f(sd));
    // numerator
    float esum = 0.f, trsum = 0.f;
    int lenc = 0;
#pragma unroll
    for (int rr = 0; rr < 8; ++rr) {
      int t = lane + 64 * rr;
      int m = mk[t];
      int lab = lb[t];
      if (m) {
        esum += sc[t * NT + lab];
        lenc += 1;
        if (t > 0) trsum += trans[lb[t - 1] * NT + lab];
      }
    }
    esum = wave_sum_f(esum);
    trsum = wave_sum_f(trsum);
    int len = wave_sum_i(lenc);
    if (lane == 0) {
      float num = startv[lb[0]] + esum + trsum + endv[lb[len - 1]];
      llh[b] = num - den;
    }
  } else {
    // ================= Viterbi for sequence b =================
    const int b = blockIdx.x - NB;
    const float* sc = scores + (size_t)b * NL * NT;
    const int* mk = maskp + b * NL;
    float* out = tags_out + (size_t)b * NL;
    __shared__ float Tl[NT * 68];               // trans, row i contiguous (stride 68)
    __shared__ unsigned char hist[NL * 68];     // argmax history

    float lmin = 1e30f, lmax = -1e30f;
    for (int idx = lane; idx < NT * NT; idx += 64) {
      float v = trans[idx];
      int i = idx / NT, j = idx - i * NT;
      Tl[i * 68 + j] = v;
      lmin = fminf(lmin, v);
      lmax = fmaxf(lmax, v);
    }
    for (int i = lane; i < NT; i += 64) Tl[i * 68 + 67] = 0.f;  // pad col
    float trmin = wave_min_f(lmin), trmax = wave_max_f(lmax);
    int lenc = 0;
#pragma unroll
    for (int rr = 0; rr < 8; ++rr) lenc += (mk[lane + 64 * rr] ? 1 : 0);
    int len = wave_sum_i(lenc);
    __syncthreads();

    const int j2col = 64 + (lane & 3);  // in-bounds (uses pad col for lane&3==3)
    float s0 = startv[lane] + sc[lane];
    float s1 = (lane < 3) ? (startv[64 + lane] + sc[64 + lane]) : -INFINITY;

    for (int t = 1; t < NL; ++t) {
      float e0 = sc[t * NT + lane];  // issue early
      float e1 = (lane < 3) ? sc[t * NT + 64 + lane] : 0.f;
      int mt = mk[t];
      // exact candidate pruning: winner i must have s_i >= Smax + trmin - trmax
      float Smax = wave_max_f(fmaxf(s0, s1));
      float thr = Smax + trmin - trmax - 1e-5f;
      unsigned long long cm = __ballot(s0 >= thr);
      unsigned em = (unsigned)(__ballot((lane < 3) && (s1 >= thr))) & 7u;
      float m0 = -INFINITY, m1 = -INFINITY;
      int a0i = 0, a1i = 0;
      while (cm) {  // ascending i + strict '>' == jnp.argmax first-index tie-break
        int c = __builtin_ctzll(cm);
        cm &= cm - 1;
        float scc = __shfl(s0, c);
        float x0 = scc + Tl[c * 68 + lane];
        float x1 = scc + Tl[c * 68 + j2col];
        if (x0 > m0) { m0 = x0; a0i = c; }
        if (x1 > m1) { m1 = x1; a1i = c; }
      }
      while (em) {
        int eb = __builtin_ctz(em);
        em &= em - 1;
        int c = 64 + eb;
        float scc = __shfl(s1, eb);
        float x0 = scc + Tl[c * 68 + lane];
        float x1 = scc + Tl[c * 68 + j2col];
        if (x0 > m0) { m0 = x0; a0i = c; }
        if (x1 > m1) { m1 = x1; a1i = c; }
      }
      hist[t * 68 + lane] = (unsigned char)a0i;
      if (lane < 3) hist[t * 68 + 64 + lane] = (unsigned char)a1i;
      if (mt) {
        s0 = m0 + e0;
        if (lane < 3) s1 = m1 + e1;
      }
    }
    // last = argmax(score + end), first-index ties
    float v0 = s0 + endv[lane];
    float v1 = (lane < 3) ? (s1 + endv[64 + lane]) : -INFINITY;
    float bv;
    int bi;
    if (v1 > v0) { bv = v1; bi = 64 + lane; } else { bv = v0; bi = lane; }
#pragma unroll
    for (int o = 32; o > 0; o >>= 1) {
      float ov = __shfl_xor(bv, o);
      int oi = __shfl_xor(bi, o);
      if (ov > bv || (ov == bv && oi < bi)) { bv = ov; bi = oi; }
    }
    __syncthreads();
    // masked tail -> 0 (parallel)
    for (int p = len + lane; p < NL; p += 64) out[p] = 0.f;
    // serial backtrace through LDS history
    if (lane == 0) {
      int cur = bi;
      for (int p = len - 1; p >= 1; --p) {
        out[p] = (float)cur;
        cur = hist[p * 68 + cur];
      }
      out[0] = (float)cur;
    }
  }
}

// ---------------- K3: loss = -sum(llh)/B ----------------
__global__ __launch_bounds__(64) void k_final(const float* __restrict__ llh,
                                              float* __restrict__ out) {
  int lane = threadIdx.x;
  float v = (lane < NB) ? llh[lane] : 0.f;
  v = wave_sum_f(v);
  if (lane == 0) out[0] = -v / (float)NB;
}

extern "C" void kernel_launch(void* const* d_in, const int* in_sizes, int n_in,
                              void* d_out, int out_size, void* d_ws, size_t ws_size,
                              hipStream_t stream) {
  const float* hidden = (const float*)d_in[0];
  const float* W = (const float*)d_in[1];
  const float* bias = (const float*)d_in[2];
  const float* startv = (const float*)d_in[3];
  const float* endv = (const float*)d_in[4];
  const float* trans = (const float*)d_in[5];
  const int* labels = (const int*)d_in[6];
  const int* maskp = (const int*)d_in[7];
  float* out = (float*)d_out;

  float* scores = (float*)d_ws;                                   // 32*512*67 f32 = 4.39 MB
  float* llh = (float*)((char*)d_ws + ((size_t)NB * NL * NT * sizeof(float) + 255 & ~(size_t)255));

  hipLaunchKernelGGL(k_scores, dim3((NB * NL) / K1_ROWS), dim3(256), 0, stream,
                     hidden, W, bias, scores);
  hipLaunchKernelGGL(k_crf_vit, dim3(2 * NB), dim3(64), 0, stream,
                     scores, trans, startv, endv, labels, maskp, llh, out + 1);
  hipLaunchKernelGGL(k_final, dim3(1), dim3(64), 0, stream, llh, out);
}

// Round 2
// 521.496 us; speedup vs baseline: 1.2113x; 1.2113x over previous
//
#include <hip/hip_runtime.h>
#include <math.h>

constexpr int NB = 32;     // batch
constexpr int NL = 512;    // seq len
constexpr int NH = 1024;   // hidden
constexpr int NT = 67;     // tags

// ---------------- shfl helpers (one-time reductions only) ----------------
__device__ __forceinline__ float wave_max_f(float v) {
#pragma unroll
  for (int o = 32; o > 0; o >>= 1) v = fmaxf(v, __shfl_xor(v, o));
  return v;
}
__device__ __forceinline__ float wave_min_f(float v) {
#pragma unroll
  for (int o = 32; o > 0; o >>= 1) v = fminf(v, __shfl_xor(v, o));
  return v;
}
__device__ __forceinline__ float wave_sum_f(float v) {
#pragma unroll
  for (int o = 32; o > 0; o >>= 1) v += __shfl_xor(v, o);
  return v;
}
__device__ __forceinline__ int wave_sum_i(int v) {
#pragma unroll
  for (int o = 32; o > 0; o >>= 1) v += __shfl_xor(v, o);
  return v;
}

// ---------------- DPP wave reductions (VALU-speed, ~60cy vs ~240cy shfl) ----
// row_shr:n = 0x110|n ; row_bcast15 = 0x142 ; row_bcast31 = 0x143
#define DPPF(OLDV, X, CTRL)                                                     \
  __int_as_float(__builtin_amdgcn_update_dpp(__float_as_int(OLDV),              \
                                             __float_as_int(X), (CTRL), 0xf,   \
                                             0xf, false))

__device__ __forceinline__ float wave_max_dpp(float x) {  // result broadcast
  x = fmaxf(x, DPPF(x, x, 0x111));
  x = fmaxf(x, DPPF(x, x, 0x112));
  x = fmaxf(x, DPPF(x, x, 0x114));
  x = fmaxf(x, DPPF(x, x, 0x118));
  x = fmaxf(x, DPPF(x, x, 0x142));
  x = fmaxf(x, DPPF(x, x, 0x143));
  return __int_as_float(__builtin_amdgcn_readlane(__float_as_int(x), 63));
}
__device__ __forceinline__ float wave_sum_dpp(float x) {  // result broadcast
  x += DPPF(0.f, x, 0x111);
  x += DPPF(0.f, x, 0x112);
  x += DPPF(0.f, x, 0x114);
  x += DPPF(0.f, x, 0x118);
  x += DPPF(0.f, x, 0x142);
  x += DPPF(0.f, x, 0x143);
  return __int_as_float(__builtin_amdgcn_readlane(__float_as_int(x), 63));
}

// s_waitcnt lgkmcnt(0) WITHOUT the vmcnt(0) drain __syncthreads() forces.
// Single-wave blocks only; consumers are LDS reads (memory ops, ordered by
// the "memory" clobber — rule #18 concerns register-only consumers).
#define LGKM_BARRIER() asm volatile("s_waitcnt lgkmcnt(0)" ::: "memory")

__device__ __forceinline__ float rdlane(float v, int l) {
  return __int_as_float(__builtin_amdgcn_readlane(__float_as_int(v), l));
}
__device__ __forceinline__ float rdfirst(float v) {
  return __int_as_float(__builtin_amdgcn_readfirstlane(__float_as_int(v)));
}

// ---------------- K1: scores = log_softmax(leaky_relu(hidden) @ W + b) ------
// 512 blocks x 256 threads; 32 rows/block (2 blocks/CU -> 2 waves/SIMD).
// Thread (r = tid&31, cg = tid>>5): row r, cols [cg*9, cg*9+9).
// A[32][65]: bank (r+k)%32 conflict-free. Wl[64][96]: 8 groups of 12
// (16B-aligned), reads = 2x ds_read_b128 + 1x b32, wave-uniform broadcast.
constexpr int K1_ROWS = 32, K1_KC = 64;

__global__ __launch_bounds__(256) void k_scores(const float* __restrict__ hidden,
                                                const float* __restrict__ W,
                                                const float* __restrict__ bias,
                                                float* __restrict__ scores) {
  __shared__ float A[K1_ROWS][K1_KC + 1];
  __shared__ float Wl[K1_KC * 96];  // reused as Lbuf[32][68] in epilogue
  __shared__ float Pm[K1_ROWS][8];
  __shared__ float Ps[K1_ROWS][8];
  __shared__ float Lse[K1_ROWS];

  const int tid = threadIdx.x;
  const int r = tid & 31;
  const int cg = tid >> 5;
  const size_t r0 = (size_t)blockIdx.x * K1_ROWS;
  const int c0 = cg * 9;

  float acc[9];
#pragma unroll
  for (int i = 0; i < 9; ++i) acc[i] = 0.f;

  for (int kc = 0; kc < NH; kc += K1_KC) {
    __syncthreads();
    // stage A: 32 rows x 64 k, leaky_relu fused (512 float4 / 256 threads)
#pragma unroll
    for (int rep = 0; rep < 2; ++rep) {
      int idx = rep * 256 + tid;
      int row = idx >> 4, c4 = idx & 15;
      float4 v = *reinterpret_cast<const float4*>(&hidden[(r0 + row) * NH + kc + c4 * 4]);
      v.x = v.x > 0.f ? v.x : 0.01f * v.x;
      v.y = v.y > 0.f ? v.y : 0.01f * v.y;
      v.z = v.z > 0.f ? v.z : 0.01f * v.z;
      v.w = v.w > 0.f ? v.w : 0.01f * v.w;
      A[row][c4 * 4 + 0] = v.x;
      A[row][c4 * 4 + 1] = v.y;
      A[row][c4 * 4 + 2] = v.z;
      A[row][c4 * 4 + 3] = v.w;
    }
    // stage W chunk: 64 x 67 coalesced, group-padded layout
#pragma unroll
    for (int rep = 0; rep < 17; ++rep) {
      int idx = rep * 256 + tid;
      if (idx < K1_KC * NT) {
        int k = idx / NT, t = idx - k * NT;
        Wl[k * 96 + (t / 9) * 12 + (t % 9)] = W[(size_t)(kc + k) * NT + t];
      }
    }
    __syncthreads();
#pragma unroll 8
    for (int k = 0; k < K1_KC; ++k) {
      float a = A[r][k];
      const float* wr = &Wl[k * 96 + cg * 12];
      float4 w0 = *reinterpret_cast<const float4*>(wr);
      float4 w1 = *reinterpret_cast<const float4*>(wr + 4);
      float w8 = wr[8];
      acc[0] = fmaf(a, w0.x, acc[0]);
      acc[1] = fmaf(a, w0.y, acc[1]);
      acc[2] = fmaf(a, w0.z, acc[2]);
      acc[3] = fmaf(a, w0.w, acc[3]);
      acc[4] = fmaf(a, w1.x, acc[4]);
      acc[5] = fmaf(a, w1.y, acc[5]);
      acc[6] = fmaf(a, w1.z, acc[6]);
      acc[7] = fmaf(a, w1.w, acc[7]);
      acc[8] = fmaf(a, w8, acc[8]);
    }
  }
  __syncthreads();

  float pm = -INFINITY;
#pragma unroll
  for (int i = 0; i < 9; ++i) {
    int t = c0 + i;
    if (t < NT) {
      acc[i] += bias[t];
      pm = fmaxf(pm, acc[i]);
    }
  }
  Pm[r][cg] = pm;
  __syncthreads();
  float M = Pm[r][0];
#pragma unroll
  for (int g = 1; g < 8; ++g) M = fmaxf(M, Pm[r][g]);
  float ps = 0.f;
#pragma unroll
  for (int i = 0; i < 9; ++i) {
    int t = c0 + i;
    if (t < NT) ps += expf(acc[i] - M);
  }
  Ps[r][cg] = ps;
  __syncthreads();
  if (cg == 0) {
    float s = 0.f;
#pragma unroll
    for (int g = 0; g < 8; ++g) s += Ps[r][g];
    Lse[r] = M + logf(s);
  }
  __syncthreads();
  float lse = Lse[r];
  float* Lb = &Wl[0];  // overlay [32][68]
#pragma unroll
  for (int i = 0; i < 9; ++i) {
    int t = c0 + i;
    if (t < NT) Lb[r * 68 + t] = acc[i] - lse;
  }
  __syncthreads();
#pragma unroll
  for (int rep = 0; rep < 9; ++rep) {
    int idx = rep * 256 + tid;
    if (idx < K1_ROWS * NT) {
      int row = idx / NT, t = idx - row * NT;
      scores[(r0 + row) * NT + t] = Lb[row * 68 + t];
    }
  }
}

// ---------------- K2: 96 blocks x 1 wave --------------------------------
// blocks  0..31: CRF forward  t=1..255  (mask-free: lengths >= 256)
// blocks 32..63: CRF backward t=511..256 (masked steps = identity)
// blocks 64..95: Viterbi full forward + hist2-accelerated backtrace
// dynamic LDS: Tl[67*68]f32 | h1[512*68]u8 | h2[512*68]u8 | pb[68]f32
constexpr int LDS_TL = NT * 68 * 4;          // 18224
constexpr int LDS_H = NL * 68;               // 34816
constexpr int LDS_TOTAL = LDS_TL + 2 * LDS_H + 68 * 4 + 16;

__global__ __launch_bounds__(64) void k_scan(const float* __restrict__ scores,
                                             const float* __restrict__ trans,
                                             const float* __restrict__ startv,
                                             const float* __restrict__ endv,
                                             const int* __restrict__ labels,
                                             const int* __restrict__ maskp,
                                             float* __restrict__ wsA,
                                             float* __restrict__ wsB,
                                             float* __restrict__ wsNum,
                                             float* __restrict__ tags_out) {
  extern __shared__ char smem[];
  const int lane = threadIdx.x;

  if (blockIdx.x < NB) {
    // ================= CRF FORWARD (no mask: t<256 always valid) ==========
    const int b = blockIdx.x;
    const float* sc = scores + (size_t)b * NL * NT;
    const int* mk = maskp + b * NL;
    const int* lb = labels + b * NL;
    float* pb = (float*)(smem + LDS_TL + 2 * LDS_H);

    // column j=lane of E=exp(trans); extra cols 64..66 distributed via DPP sums
    float ET0[NT];
#pragma unroll
    for (int i = 0; i < NT; ++i) ET0[i] = __expf(trans[i * NT + lane]);
    float E3[3], E3b[3];
    const int r2 = (lane < 3) ? (64 + lane) : 66;
#pragma unroll
    for (int k = 0; k < 3; ++k) {
      E3[k] = __expf(trans[lane * NT + 64 + k]);
      E3b[k] = (lane < 3) ? __expf(trans[r2 * NT + 64 + k]) : 0.f;
    }
    float a0 = startv[lane] + sc[lane];
    float a1 = (lane < 3) ? (startv[64 + lane] + sc[64 + lane]) : 0.f;

    float e0 = sc[NT + lane];
    float e1 = (lane < 3) ? sc[NT + 64 + lane] : 0.f;
    for (int t = 1; t < 256; ++t) {
      float e0n = 0.f, e1n = 0.f;
      if (t < 255) {  // prefetch next step's emissions
        e0n = sc[(t + 1) * NT + lane];
        e1n = (lane < 3) ? sc[(t + 1) * NT + 64 + lane] : 0.f;
      }
      float M = rdfirst(a0);  // any in-band reference works (spread << 88)
      float q = __expf(a0 - M);
      float q2 = (lane < 3) ? __expf(a1 - M) : 0.f;
      pb[lane] = q;
      if (lane < 3) pb[64 + lane] = q2;
      LGKM_BARRIER();
      float s0 = 0, s1 = 0, s2 = 0, s3 = 0;
#pragma unroll
      for (int i4 = 0; i4 < 16; ++i4) {
        float4 pv = *reinterpret_cast<const float4*>(&pb[i4 * 4]);
        s0 = fmaf(pv.x, ET0[4 * i4 + 0], s0);
        s1 = fmaf(pv.y, ET0[4 * i4 + 1], s1);
        s2 = fmaf(pv.z, ET0[4 * i4 + 2], s2);
        s3 = fmaf(pv.w, ET0[4 * i4 + 3], s3);
      }
      {
        float p64 = pb[64], p65 = pb[65], p66 = pb[66];
        s0 = fmaf(p64, ET0[64], s0);
        s1 = fmaf(p65, ET0[65], s1);
        s2 = fmaf(p66, ET0[66], s2);
      }
      float S = (s0 + s1) + (s2 + s3);
      // extra cols 64..66: one FMA per lane + DPP wave-sum (off main chain)
      float x0 = wave_sum_dpp(fmaf(q, E3[0], q2 * E3b[0]));
      float x1 = wave_sum_dpp(fmaf(q, E3[1], q2 * E3b[1]));
      float x2 = wave_sum_dpp(fmaf(q, E3[2], q2 * E3b[2]));
      a0 = e0 + M + __logf(S);
      if (lane < 3) {
        float Sx = (lane == 0) ? x0 : ((lane == 1) ? x1 : x2);
        a1 = e1 + M + __logf(Sx);
      }
      e0 = e0n;
      e1 = e1n;
    }
    wsA[b * 68 + lane] = a0;
    if (lane < 3) wsA[b * 68 + 64 + lane] = a1;

    // numerator (parallel over t)
    float esum = 0.f, trsum = 0.f;
    int lenc = 0;
#pragma unroll
    for (int rr = 0; rr < 8; ++rr) {
      int t = lane + 64 * rr;
      int m = mk[t];
      int lab = lb[t];
      if (m) {
        esum += sc[t * NT + lab];
        lenc += 1;
        if (t > 0) trsum += trans[lb[t - 1] * NT + lab];
      }
    }
    esum = wave_sum_f(esum);
    trsum = wave_sum_f(trsum);
    int len = wave_sum_i(lenc);
    if (lane == 0) wsNum[b] = startv[lb[0]] + esum + trsum + endv[lb[len - 1]];

  } else if (blockIdx.x < 2 * NB) {
    // ================= CRF BACKWARD t=511..256 ============================
    const int b = blockIdx.x - NB;
    const float* sc = scores + (size_t)b * NL * NT;
    const int* mk = maskp + b * NL;
    float* pb = (float*)(smem + LDS_TL + 2 * LDS_H);

    // row i=lane of E; extra rows 64..66 distributed via DPP sums
    float ER[NT];
#pragma unroll
    for (int j = 0; j < NT; ++j) ER[j] = __expf(trans[lane * NT + j]);
    float EC3[3], EC3b[3];
#pragma unroll
    for (int k = 0; k < 3; ++k) {
      EC3[k] = __expf(trans[(64 + k) * NT + lane]);
      EC3b[k] = (lane < 3) ? __expf(trans[(64 + k) * NT + 64 + lane]) : 0.f;
    }
    float b0 = endv[lane];
    float b1 = (lane < 3) ? endv[64 + lane] : 0.f;

    float e0 = sc[511 * NT + lane];
    float e1 = (lane < 3) ? sc[511 * NT + 64 + lane] : 0.f;
    int mt = mk[511];
    for (int t = 511; t >= 256; --t) {
      float e0n = 0.f, e1n = 0.f;
      int mtn = 0;
      if (t > 256) {
        e0n = sc[(t - 1) * NT + lane];
        e1n = (lane < 3) ? sc[(t - 1) * NT + 64 + lane] : 0.f;
        mtn = mk[t - 1];
      }
      float u = e0 + b0;
      float u2 = (lane < 3) ? (e1 + b1) : 0.f;
      float M = rdfirst(u);
      float q = __expf(u - M);
      float q2 = (lane < 3) ? __expf(u2 - M) : 0.f;
      pb[lane] = q;
      if (lane < 3) pb[64 + lane] = q2;
      LGKM_BARRIER();
      float s0 = 0, s1 = 0, s2 = 0, s3 = 0;
#pragma unroll
      for (int i4 = 0; i4 < 16; ++i4) {
        float4 pv = *reinterpret_cast<const float4*>(&pb[i4 * 4]);
        s0 = fmaf(pv.x, ER[4 * i4 + 0], s0);
        s1 = fmaf(pv.y, ER[4 * i4 + 1], s1);
        s2 = fmaf(pv.z, ER[4 * i4 + 2], s2);
        s3 = fmaf(pv.w, ER[4 * i4 + 3], s3);
      }
      {
        float p64 = pb[64], p65 = pb[65], p66 = pb[66];
        s0 = fmaf(p64, ER[64], s0);
        s1 = fmaf(p65, ER[65], s1);
        s2 = fmaf(p66, ER[66], s2);
      }
      float S = (s0 + s1) + (s2 + s3);
      float x0 = wave_sum_dpp(fmaf(q, EC3[0], q2 * EC3b[0]));
      float x1 = wave_sum_dpp(fmaf(q, EC3[1], q2 * EC3b[1]));
      float x2 = wave_sum_dpp(fmaf(q, EC3[2], q2 * EC3b[2]));
      if (mt) {
        b0 = M + __logf(S);
        if (lane < 3) {
          float Sx = (lane == 0) ? x0 : ((lane == 1) ? x1 : x2);
          b1 = M + __logf(Sx);
        }
      }
      e0 = e0n;
      e1 = e1n;
      mt = mtn;
    }
    wsB[b * 68 + lane] = b0;
    if (lane < 3) wsB[b * 68 + 64 + lane] = b1;

  } else {
    // ================= VITERBI =============================================
    const int b = blockIdx.x - 2 * NB;
    const float* sc = scores + (size_t)b * NL * NT;
    const int* mk = maskp + b * NL;
    float* out = tags_out + (size_t)b * NL;
    float* Tl = (float*)smem;
    unsigned char* h1 = (unsigned char*)(smem + LDS_TL);
    unsigned char* h2 = h1 + LDS_H;

    float lmin = 1e30f, lmax = -1e30f;
    for (int idx = lane; idx < NT * NT; idx += 64) {
      float v = trans[idx];
      int i = idx / NT, j = idx - i * NT;
      Tl[i * 68 + j] = v;
      lmin = fminf(lmin, v);
      lmax = fmaxf(lmax, v);
    }
    for (int i = lane; i < NT; i += 64) Tl[i * 68 + 67] = 0.f;  // pad col
    float trspan = wave_min_f(lmin) - wave_max_f(lmax) - 1e-5f;
    int lenc = 0;
#pragma unroll
    for (int rr = 0; rr < 8; ++rr) lenc += (mk[lane + 64 * rr] ? 1 : 0);
    int len = wave_sum_i(lenc);
    __syncthreads();

    const int j2col = 64 + (lane & 3);  // pad col for lane&3==3
    float s0 = startv[lane] + sc[lane];
    float s1 = (lane < 3) ? (startv[64 + lane] + sc[64 + lane]) : -INFINITY;
    int pa0 = 0, pa1 = 0;

    float e0 = sc[NT + lane];
    float e1 = (lane < 3) ? sc[NT + 64 + lane] : 0.f;
    for (int t = 1; t < NL; ++t) {
      float e0n = 0.f, e1n = 0.f;
      if (t < NL - 1) {
        e0n = sc[(t + 1) * NT + lane];
        e1n = (lane < 3) ? sc[(t + 1) * NT + 64 + lane] : 0.f;
      }
      int mt = mk[t];
      // exact pruning: winner i needs s_i >= Smax + trmin - trmax
      float Smax = wave_max_dpp(fmaxf(s0, s1));
      float thr = Smax + trspan;
      unsigned long long cm = __ballot(s0 >= thr);
      unsigned em = (unsigned)(__ballot((lane < 3) && (s1 >= thr))) & 7u;
      float m0 = -INFINITY, m1 = -INFINITY;
      int a0i = 0, a1i = 0;
      while (cm) {  // ascending i + strict '>' == first-index argmax
        int c = (int)__builtin_ctzll(cm);
        cm &= cm - 1;
        float scc = rdlane(s0, c);
        float x0 = scc + Tl[c * 68 + lane];
        float x1 = scc + Tl[c * 68 + j2col];
        if (x0 > m0) { m0 = x0; a0i = c; }
        if (x1 > m1) { m1 = x1; a1i = c; }
      }
      while (em) {
        int eb = (int)__builtin_ctz(em);
        em &= em - 1;
        int c = 64 + eb;
        float scc = rdlane(s1, eb);
        float x0 = scc + Tl[c * 68 + lane];
        float x1 = scc + Tl[c * 68 + j2col];
        if (x0 > m0) { m0 = x0; a0i = c; }
        if (x1 > m1) { m1 = x1; a1i = c; }
      }
      h1[t * 68 + lane] = (unsigned char)a0i;
      if (lane < 3) h1[t * 68 + 64 + lane] = (unsigned char)a1i;
      // 2-step composed history (exact; off the s-chain). h2[1] unused.
      int g0 = __shfl(pa0, a0i & 63);
      int g0b = __shfl(pa1, (a0i >= 64) ? (a0i - 64) : 0);
      int hv = (a0i < 64) ? g0 : g0b;
      int g1 = __shfl(pa0, a1i & 63);
      int g1b = __shfl(pa1, (a1i >= 64) ? (a1i - 64) : 0);
      int hvb = (a1i < 64) ? g1 : g1b;
      h2[t * 68 + lane] = (unsigned char)hv;
      if (lane < 3) h2[t * 68 + 64 + lane] = (unsigned char)hvb;
      pa0 = a0i;
      pa1 = a1i;
      if (mt) {
        s0 = m0 + e0;
        if (lane < 3) s1 = m1 + e1;
      }
      e0 = e0n;
      e1 = e1n;
    }
    // last = argmax(score + end), first-index ties
    float v0 = s0 + endv[lane];
    float v1 = (lane < 3) ? (s1 + endv[64 + lane]) : -INFINITY;
    float bv;
    int bi;
    if (v1 > v0) { bv = v1; bi = 64 + lane; } else { bv = v0; bi = lane; }
#pragma unroll
    for (int o = 32; o > 0; o >>= 1) {
      float ov = __shfl_xor(bv, o);
      int oi = __shfl_xor(bi, o);
      if (ov > bv || (ov == bv && oi < bi)) { bv = ov; bi = oi; }
    }
    __syncthreads();
    for (int p = len + lane; p < NL; p += 64) out[p] = 0.f;
    // two parallel backtrace chains over the 2-step composed history
    if (lane < 2) {
      int p, cur;
      if (lane == 0) {
        p = len - 1;
        cur = bi;
      } else {
        p = len - 2;
        cur = h1[(len - 1) * 68 + bi];
      }
      while (p >= 2) {
        out[p] = (float)cur;
        cur = h2[p * 68 + cur];
        p -= 2;
      }
      if (p == 1) {
        out[1] = (float)cur;
        out[0] = (float)h1[68 + cur];
      } else {
        out[0] = (float)cur;  // p == 0 (both chains agree on out[0])
      }
    }
  }
}

// ---------------- K3: den = lse(alpha+B); loss = -sum(num-den)/B ----------
__global__ __launch_bounds__(256) void k_final(const float* __restrict__ wsA,
                                               const float* __restrict__ wsB,
                                               const float* __restrict__ wsNum,
                                               float* __restrict__ out) {
  const int tid = threadIdx.x;
  const int w = tid >> 6, lane = tid & 63;
  float acc = 0.f;
  for (int s = w; s < NB; s += 4) {
    float v = wsA[s * 68 + lane] + wsB[s * 68 + lane];
    float v2 = (lane < 3) ? (wsA[s * 68 + 64 + lane] + wsB[s * 68 + 64 + lane])
                          : -INFINITY;
    float M = wave_max_dpp(fmaxf(v, v2));
    float e = __expf(v - M) + ((lane < 3) ? __expf(v2 - M) : 0.f);
    float den = M + __logf(wave_sum_dpp(e));
    acc += wsNum[s] - den;
  }
  __shared__ float part[4];
  if (lane == 0) part[w] = acc;
  __syncthreads();
  if (tid == 0) out[0] = -(part[0] + part[1] + part[2] + part[3]) / (float)NB;
}

extern "C" void kernel_launch(void* const* d_in, const int* in_sizes, int n_in,
                              void* d_out, int out_size, void* d_ws, size_t ws_size,
                              hipStream_t stream) {
  const float* hidden = (const float*)d_in[0];
  const float* W = (const float*)d_in[1];
  const float* bias = (const float*)d_in[2];
  const float* startv = (const float*)d_in[3];
  const float* endv = (const float*)d_in[4];
  const float* trans = (const float*)d_in[5];
  const int* labels = (const int*)d_in[6];
  const int* maskp = (const int*)d_in[7];
  float* out = (float*)d_out;

  float* scores = (float*)d_ws;  // 32*512*67 f32 = 4.39 MB
  float* wsA = scores + (size_t)NB * NL * NT;
  float* wsB = wsA + NB * 68;
  float* wsNum = wsB + NB * 68;

  hipLaunchKernelGGL(k_scores, dim3((NB * NL) / K1_ROWS), dim3(256), 0, stream,
                     hidden, W, bias, scores);
  hipLaunchKernelGGL(k_scan, dim3(3 * NB), dim3(64), LDS_TOTAL, stream,
                     scores, trans, startv, endv, labels, maskp,
                     wsA, wsB, wsNum, out + 1);
  hipLaunchKernelGGL(k_final, dim3(1), dim3(256), 0, stream,
                     wsA, wsB, wsNum, out);
}

// Round 4
// 385.141 us; speedup vs baseline: 1.6401x; 1.3540x over previous
//
#include <hip/hip_runtime.h>
#include <math.h>

constexpr int NB = 32;     // batch
constexpr int NL = 512;    // seq len
constexpr int NH = 1024;   // hidden
constexpr int NT = 67;     // tags

// ---------------- shfl helpers ----------------
__device__ __forceinline__ float wave_max_f(float v) {
#pragma unroll
  for (int o = 32; o > 0; o >>= 1) v = fmaxf(v, __shfl_xor(v, o));
  return v;
}
__device__ __forceinline__ float wave_min_f(float v) {
#pragma unroll
  for (int o = 32; o > 0; o >>= 1) v = fminf(v, __shfl_xor(v, o));
  return v;
}
__device__ __forceinline__ float wave_sum_f(float v) {
#pragma unroll
  for (int o = 32; o > 0; o >>= 1) v += __shfl_xor(v, o);
  return v;
}
__device__ __forceinline__ int wave_sum_i(int v) {
#pragma unroll
  for (int o = 32; o > 0; o >>= 1) v += __shfl_xor(v, o);
  return v;
}

// ---------------- DPP wave reductions ----------------
#define DPPF(OLDV, X, CTRL)                                                     \
  __int_as_float(__builtin_amdgcn_update_dpp(__float_as_int(OLDV),              \
                                             __float_as_int(X), (CTRL), 0xf,   \
                                             0xf, false))

__device__ __forceinline__ float wave_max_dpp(float x) {  // exact max, broadcast
  x = fmaxf(x, DPPF(x, x, 0x111));
  x = fmaxf(x, DPPF(x, x, 0x112));
  x = fmaxf(x, DPPF(x, x, 0x114));
  x = fmaxf(x, DPPF(x, x, 0x118));
  x = fmaxf(x, DPPF(x, x, 0x142));
  x = fmaxf(x, DPPF(x, x, 0x143));
  return __int_as_float(__builtin_amdgcn_readlane(__float_as_int(x), 63));
}
__device__ __forceinline__ float wave_sum_dpp(float x) {  // broadcast
  x += DPPF(0.f, x, 0x111);
  x += DPPF(0.f, x, 0x112);
  x += DPPF(0.f, x, 0x114);
  x += DPPF(0.f, x, 0x118);
  x += DPPF(0.f, x, 0x142);
  x += DPPF(0.f, x, 0x143);
  return __int_as_float(__builtin_amdgcn_readlane(__float_as_int(x), 63));
}

// lgkmcnt-only wait (avoids __syncthreads' vmcnt(0) drain). Single-wave use;
// consumers are LDS reads (memory ops — ordered by the "memory" clobber).
#define LGKM_BARRIER() asm volatile("s_waitcnt lgkmcnt(0)" ::: "memory")

__device__ __forceinline__ float rdlane(float v, int l) {
  return __int_as_float(__builtin_amdgcn_readlane(__float_as_int(v), l));
}
__device__ __forceinline__ float rdfirst(float v) {
  return __int_as_float(__builtin_amdgcn_readfirstlane(__float_as_int(v)));
}

// ---------------- K1: scores = log_softmax(leaky_relu(hidden) @ W + b) ------
// 1024 blocks x 256 threads; 16 rows/block -> 4 blocks/CU = 4 waves/SIMD.
// Thread (r=tid&15, cg=tid>>4): row r, cols [cg*5, cg*5+5).
// A[16][65]: banks (r+k)%32, conflict-free broadcast. Wg: 16 groups * 6 words
// per k (2xds_read_b64 + 1xb32, group-uniform per 16 lanes, conflict-free).
// K-accumulation order identical to the validated R2 kernel (bitwise logits).
constexpr int KR = 16, KC = 64;

__global__ __launch_bounds__(256) void k_scores(const float* __restrict__ hidden,
                                                const float* __restrict__ W,
                                                const float* __restrict__ bias,
                                                float* __restrict__ scores) {
  __shared__ float A[KR][KC + 1];
  __shared__ float Wg[KC * 96];  // overlay Lb[16][68] in epilogue
  __shared__ float Pm[KR][17];
  __shared__ float Ps[KR][17];
  __shared__ float Lse[KR];

  const int tid = threadIdx.x;
  const int r = tid & 15;
  const int cg = tid >> 4;  // 0..15
  const int c0 = cg * 5;
  const size_t r0 = (size_t)blockIdx.x * KR;

  float acc0 = 0.f, acc1 = 0.f, acc2 = 0.f, acc3 = 0.f, acc4 = 0.f;

  for (int kc = 0; kc < NH; kc += KC) {
    __syncthreads();
    {  // stage A: 16 rows x 64 k, one float4 per thread, leaky_relu fused
      int row = tid >> 4, c4 = tid & 15;
      float4 v = *reinterpret_cast<const float4*>(&hidden[(r0 + row) * NH + kc + c4 * 4]);
      v.x = v.x > 0.f ? v.x : 0.01f * v.x;
      v.y = v.y > 0.f ? v.y : 0.01f * v.y;
      v.z = v.z > 0.f ? v.z : 0.01f * v.z;
      v.w = v.w > 0.f ? v.w : 0.01f * v.w;
      A[row][c4 * 4 + 0] = v.x;
      A[row][c4 * 4 + 1] = v.y;
      A[row][c4 * 4 + 2] = v.z;
      A[row][c4 * 4 + 3] = v.w;
    }
    // stage W chunk: 64 x 67 coalesced -> group-padded layout
#pragma unroll
    for (int rep = 0; rep < 17; ++rep) {
      int idx = rep * 256 + tid;
      if (idx < KC * NT) {
        int k = idx / NT, t = idx - k * NT;
        int g = t / 5, m = t - g * 5;
        Wg[k * 96 + g * 6 + m] = W[(size_t)(kc + k) * NT + t];
      }
    }
    __syncthreads();
#pragma unroll 4
    for (int k = 0; k < KC; ++k) {
      float a = A[r][k];
      const float* wr = &Wg[k * 96 + cg * 6];
      float2 wa = *reinterpret_cast<const float2*>(wr);
      float2 wb = *reinterpret_cast<const float2*>(wr + 2);
      float w4 = wr[4];
      acc0 = fmaf(a, wa.x, acc0);
      acc1 = fmaf(a, wa.y, acc1);
      acc2 = fmaf(a, wb.x, acc2);
      acc3 = fmaf(a, wb.y, acc3);
      acc4 = fmaf(a, w4, acc4);
    }
  }
  __syncthreads();

  float acc[5] = {acc0, acc1, acc2, acc3, acc4};
  float pm = -INFINITY;
#pragma unroll
  for (int i = 0; i < 5; ++i) {
    int t = c0 + i;
    if (t < NT) {
      acc[i] += bias[t];
      pm = fmaxf(pm, acc[i]);
    }
  }
  Pm[r][cg] = pm;
  __syncthreads();
  float M = -INFINITY;
#pragma unroll
  for (int g = 0; g < 16; ++g) M = fmaxf(M, Pm[r][g]);
  float ps = 0.f;
#pragma unroll
  for (int i = 0; i < 5; ++i) {
    int t = c0 + i;
    if (t < NT) ps += expf(acc[i] - M);
  }
  Ps[r][cg] = ps;
  __syncthreads();
  if (cg == 0) {
    float s = 0.f;
#pragma unroll
    for (int g = 0; g < 16; ++g) s += Ps[r][g];
    Lse[r] = M + logf(s);
  }
  __syncthreads();
  float lse = Lse[r];
  float* Lb = &Wg[0];  // overlay [16][68]
#pragma unroll
  for (int i = 0; i < 5; ++i) {
    int t = c0 + i;
    if (t < NT) Lb[r * 68 + t] = acc[i] - lse;
  }
  __syncthreads();
#pragma unroll
  for (int rep = 0; rep < 5; ++rep) {
    int idx = rep * 256 + tid;
    if (idx < KR * NT) {
      int row = idx / NT, t = idx - row * NT;
      scores[(r0 + row) * NT + t] = Lb[row * 68 + t];
    }
  }
}

// ---------------- K2: 64 blocks x 128 threads ------------------------------
// blocks  0..31: CRF  (wave0: forward t=1..255; wave1: backward t=511..256)
// blocks 32..63: Viterbi (wave0: forward half; wave1: backward half + junction)
// Viterbi dynamic LDS layout (bytes):
constexpr int VOF_TL = 0;             // f32 Tl[68][68] (row 67 / col 67 = pad 0)
constexpr int VOF_H1 = 18496;         // u8  h1f[256][68]  (fwd backptrs, t=1..255)
constexpr int VOF_GP = 35904;         // u8  gp[256][68]   (bwd fwd-ptrs, idx t-256)
constexpr int VOF_FJ = 53312;         // f32 fj[68]
constexpr int VOF_BJ = 53584;         // f32 bj[68]
constexpr int VOF_JP = 53856;         // i32 jp[68]
constexpr int VOF_JI = 54128;         // i32 ji[4]
constexpr int LDSV = 54144;

__global__ __launch_bounds__(128) void k_scan(const float* __restrict__ scores,
                                              const float* __restrict__ trans,
                                              const float* __restrict__ startv,
                                              const float* __restrict__ endv,
                                              const int* __restrict__ labels,
                                              const int* __restrict__ maskp,
                                              float* __restrict__ wsA,
                                              float* __restrict__ wsB,
                                              float* __restrict__ wsNum,
                                              float* __restrict__ tags_out) {
  extern __shared__ char smem[];
  const int lane = threadIdx.x & 63;
  const int wid = threadIdx.x >> 6;

  if (blockIdx.x < NB) {
    // ===================== CRF =====================
    const int b = blockIdx.x;
    const float* sc = scores + (size_t)b * NL * NT;
    const int* mk = maskp + b * NL;

    if (wid == 0) {
      // ---- forward t=1..255 (mask-free: lengths >= 256) ----
      const int* lb = labels + b * NL;
      float* pb = (float*)(smem);

      float ET0[NT];
#pragma unroll
      for (int i = 0; i < NT; ++i) ET0[i] = __expf(trans[i * NT + lane]);
      float E3[3], E3b[3];
      const int r2 = (lane < 3) ? (64 + lane) : 66;
#pragma unroll
      for (int k = 0; k < 3; ++k) {
        E3[k] = __expf(trans[lane * NT + 64 + k]);
        E3b[k] = (lane < 3) ? __expf(trans[r2 * NT + 64 + k]) : 0.f;
      }
      float a0 = startv[lane] + sc[lane];
      float a1 = (lane < 3) ? (startv[64 + lane] + sc[64 + lane]) : 0.f;

      float e0 = sc[NT + lane];
      float e1 = (lane < 3) ? sc[NT + 64 + lane] : 0.f;
      for (int t = 1; t < 256; ++t) {
        float e0n = 0.f, e1n = 0.f;
        if (t < 255) {
          e0n = sc[(t + 1) * NT + lane];
          e1n = (lane < 3) ? sc[(t + 1) * NT + 64 + lane] : 0.f;
        }
        float M = rdfirst(a0);
        float q = __expf(a0 - M);
        float q2 = (lane < 3) ? __expf(a1 - M) : 0.f;
        pb[lane] = q;
        if (lane < 3) pb[64 + lane] = q2;
        LGKM_BARRIER();
        float s0 = 0, s1 = 0, s2 = 0, s3 = 0;
#pragma unroll
        for (int i4 = 0; i4 < 16; ++i4) {
          float4 pv = *reinterpret_cast<const float4*>(&pb[i4 * 4]);
          s0 = fmaf(pv.x, ET0[4 * i4 + 0], s0);
          s1 = fmaf(pv.y, ET0[4 * i4 + 1], s1);
          s2 = fmaf(pv.z, ET0[4 * i4 + 2], s2);
          s3 = fmaf(pv.w, ET0[4 * i4 + 3], s3);
        }
        {
          float p64 = pb[64], p65 = pb[65], p66 = pb[66];
          s0 = fmaf(p64, ET0[64], s0);
          s1 = fmaf(p65, ET0[65], s1);
          s2 = fmaf(p66, ET0[66], s2);
        }
        float S = (s0 + s1) + (s2 + s3);
        float x0 = wave_sum_dpp(fmaf(q, E3[0], q2 * E3b[0]));
        float x1 = wave_sum_dpp(fmaf(q, E3[1], q2 * E3b[1]));
        float x2 = wave_sum_dpp(fmaf(q, E3[2], q2 * E3b[2]));
        a0 = e0 + M + __logf(S);
        if (lane < 3) {
          float Sx = (lane == 0) ? x0 : ((lane == 1) ? x1 : x2);
          a1 = e1 + M + __logf(Sx);
        }
        e0 = e0n;
        e1 = e1n;
      }
      wsA[b * 68 + lane] = a0;
      if (lane < 3) wsA[b * 68 + 64 + lane] = a1;

      // numerator (parallel over t)
      float esum = 0.f, trsum = 0.f;
      int lenc = 0;
#pragma unroll
      for (int rr = 0; rr < 8; ++rr) {
        int t = lane + 64 * rr;
        int m = mk[t];
        int lab = lb[t];
        if (m) {
          esum += sc[t * NT + lab];
          lenc += 1;
          if (t > 0) trsum += trans[lb[t - 1] * NT + lab];
        }
      }
      esum = wave_sum_f(esum);
      trsum = wave_sum_f(trsum);
      int len = wave_sum_i(lenc);
      if (lane == 0) wsNum[b] = startv[lb[0]] + esum + trsum + endv[lb[len - 1]];
    } else {
      // ---- backward t=511..256 (masked steps = identity) ----
      float* pb = (float*)(smem + 512);

      float ER[NT];
#pragma unroll
      for (int j = 0; j < NT; ++j) ER[j] = __expf(trans[lane * NT + j]);
      float EC3[3], EC3b[3];
#pragma unroll
      for (int k = 0; k < 3; ++k) {
        EC3[k] = __expf(trans[(64 + k) * NT + lane]);
        EC3b[k] = (lane < 3) ? __expf(trans[(64 + k) * NT + 64 + lane]) : 0.f;
      }
      float b0 = endv[lane];
      float b1 = (lane < 3) ? endv[64 + lane] : 0.f;

      float e0 = sc[511 * NT + lane];
      float e1 = (lane < 3) ? sc[511 * NT + 64 + lane] : 0.f;
      int mt = mk[511];
      for (int t = 511; t >= 256; --t) {
        float e0n = 0.f, e1n = 0.f;
        int mtn = 0;
        if (t > 256) {
          e0n = sc[(t - 1) * NT + lane];
          e1n = (lane < 3) ? sc[(t - 1) * NT + 64 + lane] : 0.f;
          mtn = mk[t - 1];
        }
        float u = e0 + b0;
        float u2 = (lane < 3) ? (e1 + b1) : 0.f;
        float M = rdfirst(u);
        float q = __expf(u - M);
        float q2 = (lane < 3) ? __expf(u2 - M) : 0.f;
        pb[lane] = q;
        if (lane < 3) pb[64 + lane] = q2;
        LGKM_BARRIER();
        float s0 = 0, s1 = 0, s2 = 0, s3 = 0;
#pragma unroll
        for (int i4 = 0; i4 < 16; ++i4) {
          float4 pv = *reinterpret_cast<const float4*>(&pb[i4 * 4]);
          s0 = fmaf(pv.x, ER[4 * i4 + 0], s0);
          s1 = fmaf(pv.y, ER[4 * i4 + 1], s1);
          s2 = fmaf(pv.z, ER[4 * i4 + 2], s2);
          s3 = fmaf(pv.w, ER[4 * i4 + 3], s3);
        }
        {
          float p64 = pb[64], p65 = pb[65], p66 = pb[66];
          s0 = fmaf(p64, ER[64], s0);
          s1 = fmaf(p65, ER[65], s1);
          s2 = fmaf(p66, ER[66], s2);
        }
        float S = (s0 + s1) + (s2 + s3);
        float x0 = wave_sum_dpp(fmaf(q, EC3[0], q2 * EC3b[0]));
        float x1 = wave_sum_dpp(fmaf(q, EC3[1], q2 * EC3b[1]));
        float x2 = wave_sum_dpp(fmaf(q, EC3[2], q2 * EC3b[2]));
        if (mt) {
          b0 = M + __logf(S);
          if (lane < 3) {
            float Sx = (lane == 0) ? x0 : ((lane == 1) ? x1 : x2);
            b1 = M + __logf(Sx);
          }
        }
        e0 = e0n;
        e1 = e1n;
        mt = mtn;
      }
      wsB[b * 68 + lane] = b0;
      if (lane < 3) wsB[b * 68 + 64 + lane] = b1;
    }
  } else {
    // ===================== Viterbi (bidirectional) =====================
    const int b = blockIdx.x - NB;
    const float* sc = scores + (size_t)b * NL * NT;
    const int* mk = maskp + b * NL;
    float* out = tags_out + (size_t)b * NL;
    float* Tl = (float*)(smem + VOF_TL);
    unsigned char* h1f = (unsigned char*)(smem + VOF_H1);
    unsigned char* gp = (unsigned char*)(smem + VOF_GP);
    float* fj = (float*)(smem + VOF_FJ);
    float* bj = (float*)(smem + VOF_BJ);
    int* jp = (int*)(smem + VOF_JP);
    int* ji = (int*)(smem + VOF_JI);

    // cooperative stage of Tl (+ zero pads)
    for (int idx = threadIdx.x; idx < NT * NT; idx += 128) {
      int i = idx / NT, j = idx - i * NT;
      Tl[i * 68 + j] = trans[idx];
    }
    for (int idx = threadIdx.x; idx < 68; idx += 128) {
      Tl[idx * 68 + 67] = 0.f;
      Tl[67 * 68 + idx] = 0.f;
    }
    __syncthreads();

    // per-wave: trspan from staged Tl, len from mask
    float lmin = 1e30f, lmax = -1e30f;
    for (int idx = lane; idx < NT * NT; idx += 64) {
      int i = idx / NT, j = idx - i * NT;
      float v = Tl[i * 68 + j];
      lmin = fminf(lmin, v);
      lmax = fmaxf(lmax, v);
    }
    const float trspan = wave_min_f(lmin) - wave_max_f(lmax) - 1e-5f;
    int lenc = 0;
#pragma unroll
    for (int rr = 0; rr < 8; ++rr) lenc += (mk[lane + 64 * rr] ? 1 : 0);
    const int len = wave_sum_i(lenc);

    if (wid == 0) {
      // ---- forward half t=1..255 (always active) ----
      const int j2col = 64 + (lane & 3);  // pad col for lane&3==3
      float s0 = startv[lane] + sc[lane];
      float s1 = (lane < 3) ? (startv[64 + lane] + sc[64 + lane]) : -INFINITY;
      for (int t = 1; t < 256; ++t) {
        float e0 = sc[t * NT + lane];
        float e1 = (lane < 3) ? sc[t * NT + 64 + lane] : 0.f;
        float Smax = wave_max_dpp(fmaxf(s0, s1));
        float thr = Smax + trspan;
        unsigned long long cm = __ballot(s0 >= thr);
        unsigned em = (unsigned)__ballot((lane < 3) && (s1 >= thr)) & 7u;
        float m0 = -INFINITY, m1 = -INFINITY;
        int a0i = 0, a1i = 0;
        while (cm) {  // batch of 4 candidates, ascending, strict '>'
          int c0 = (int)__builtin_ctzll(cm);
          unsigned long long n1 = cm & (cm - 1);
          int c1 = n1 ? (int)__builtin_ctzll(n1) : c0;
          unsigned long long n2 = n1 ? (n1 & (n1 - 1)) : 0;
          int c2 = n2 ? (int)__builtin_ctzll(n2) : c0;
          unsigned long long n3 = n2 ? (n2 & (n2 - 1)) : 0;
          int c3 = n3 ? (int)__builtin_ctzll(n3) : c0;
          cm = n3 ? (n3 & (n3 - 1)) : 0;
          float ta0 = Tl[c0 * 68 + lane], tb0 = Tl[c0 * 68 + j2col];
          float ta1 = Tl[c1 * 68 + lane], tb1 = Tl[c1 * 68 + j2col];
          float ta2 = Tl[c2 * 68 + lane], tb2 = Tl[c2 * 68 + j2col];
          float ta3 = Tl[c3 * 68 + lane], tb3 = Tl[c3 * 68 + j2col];
          float v0 = rdlane(s0, c0), v1 = rdlane(s0, c1);
          float v2 = rdlane(s0, c2), v3 = rdlane(s0, c3);
          float x;
          x = v0 + ta0; if (x > m0) { m0 = x; a0i = c0; }
          x = v1 + ta1; if (x > m0) { m0 = x; a0i = c1; }
          x = v2 + ta2; if (x > m0) { m0 = x; a0i = c2; }
          x = v3 + ta3; if (x > m0) { m0 = x; a0i = c3; }
          x = v0 + tb0; if (x > m1) { m1 = x; a1i = c0; }
          x = v1 + tb1; if (x > m1) { m1 = x; a1i = c1; }
          x = v2 + tb2; if (x > m1) { m1 = x; a1i = c2; }
          x = v3 + tb3; if (x > m1) { m1 = x; a1i = c3; }
        }
        while (em) {
          int eb = (int)__builtin_ctz(em);
          em &= em - 1;
          int c = 64 + eb;
          float scc = rdlane(s1, eb);
          float x0 = scc + Tl[c * 68 + lane];
          float x1 = scc + Tl[c * 68 + j2col];
          if (x0 > m0) { m0 = x0; a0i = c; }
          if (x1 > m1) { m1 = x1; a1i = c; }
        }
        h1f[t * 68 + lane] = (unsigned char)a0i;
        if (lane < 3) h1f[t * 68 + 64 + lane] = (unsigned char)a1i;
        s0 = m0 + e0;
        if (lane < 3) s1 = m1 + e1;
      }
      fj[lane] = s0;
      if (lane < 3) fj[64 + lane] = s1;
      __syncthreads();  // #1: scans done
      __syncthreads();  // #2: junction done
      int jstar = ji[0];
      for (int p = len + lane; p < NL; p += 64) out[p] = 0.f;
      if (lane == 0) {
        int cur = jstar;
        for (int p = 255; p >= 1; --p) {
          out[p] = (float)cur;
          cur = h1f[p * 68 + cur];
        }
        out[0] = (float)cur;
      }
    } else {
      // ---- backward half: b(t,i), fwd-pointers gp; then junction ----
      const int i2 = 64 + (lane & 3);  // pad row for lane&3==3
      float b0 = 0.f, b1 = -INFINITY;
      if (len > 256) {
        b0 = sc[(size_t)(len - 1) * NT + lane] + endv[lane];
        b1 = (lane < 3) ? (sc[(size_t)(len - 1) * NT + 64 + lane] + endv[64 + lane])
                        : -INFINITY;
        for (int t = len - 2; t >= 256; --t) {
          float e0 = sc[t * NT + lane];
          float e1 = (lane < 3) ? sc[t * NT + 64 + lane] : 0.f;
          float Bmax = wave_max_dpp(fmaxf(b0, b1));
          float thr = Bmax + trspan;
          unsigned long long cm = __ballot(b0 >= thr);
          unsigned em = (unsigned)__ballot((lane < 3) && (b1 >= thr)) & 7u;
          float m0 = -INFINITY, m1 = -INFINITY;
          int a0i = 0, a1i = 0;
          while (cm) {
            int c0 = (int)__builtin_ctzll(cm);
            unsigned long long n1 = cm & (cm - 1);
            int c1 = n1 ? (int)__builtin_ctzll(n1) : c0;
            unsigned long long n2 = n1 ? (n1 & (n1 - 1)) : 0;
            int c2 = n2 ? (int)__builtin_ctzll(n2) : c0;
            unsigned long long n3 = n2 ? (n2 & (n2 - 1)) : 0;
            int c3 = n3 ? (int)__builtin_ctzll(n3) : c0;
            cm = n3 ? (n3 & (n3 - 1)) : 0;
            float ta0 = Tl[lane * 68 + c0], tb0 = Tl[i2 * 68 + c0];
            float ta1 = Tl[lane * 68 + c1], tb1 = Tl[i2 * 68 + c1];
            float ta2 = Tl[lane * 68 + c2], tb2 = Tl[i2 * 68 + c2];
            float ta3 = Tl[lane * 68 + c3], tb3 = Tl[i2 * 68 + c3];
            float v0 = rdlane(b0, c0), v1 = rdlane(b0, c1);
            float v2 = rdlane(b0, c2), v3 = rdlane(b0, c3);
            float x;
            x = v0 + ta0; if (x > m0) { m0 = x; a0i = c0; }
            x = v1 + ta1; if (x > m0) { m0 = x; a0i = c1; }
            x = v2 + ta2; if (x > m0) { m0 = x; a0i = c2; }
            x = v3 + ta3; if (x > m0) { m0 = x; a0i = c3; }
            x = v0 + tb0; if (x > m1) { m1 = x; a1i = c0; }
            x = v1 + tb1; if (x > m1) { m1 = x; a1i = c1; }
            x = v2 + tb2; if (x > m1) { m1 = x; a1i = c2; }
            x = v3 + tb3; if (x > m1) { m1 = x; a1i = c3; }
          }
          while (em) {
            int eb = (int)__builtin_ctz(em);
            em &= em - 1;
            int c = 64 + eb;
            float scc = rdlane(b1, eb);
            float x0 = scc + Tl[lane * 68 + c];
            float x1 = scc + Tl[i2 * 68 + c];
            if (x0 > m0) { m0 = x0; a0i = c; }
            if (x1 > m1) { m1 = x1; a1i = c; }
          }
          gp[(t + 1 - 256) * 68 + lane] = (unsigned char)a0i;
          if (lane < 3) gp[(t + 1 - 256) * 68 + 64 + lane] = (unsigned char)a1i;
          b0 = e0 + m0;
          if (lane < 3) b1 = e1 + m1;
        }
        bj[lane] = b0;
        if (lane < 3) bj[64 + lane] = b1;
      }
      __syncthreads();  // #1: scans done (fj/bj visible)
      // junction: c(i) = max_j(T_ij + b256(j)) (or end_i if len==256)
      float ci, ci2;
      int jpi = 0, jpi2 = 0;
      if (len > 256) {
        ci = -INFINITY;
        ci2 = -INFINITY;
        for (int j = 0; j < NT; ++j) {
          float bv = bj[j];
          float x = Tl[lane * 68 + j] + bv;
          if (x > ci) { ci = x; jpi = j; }
          if (lane < 3) {
            float x2 = Tl[(64 + lane) * 68 + j] + bv;
            if (x2 > ci2) { ci2 = x2; jpi2 = j; }
          }
        }
      } else {
        ci = endv[lane];
        ci2 = (lane < 3) ? endv[64 + lane] : -INFINITY;
      }
      float v0 = fj[lane] + ci;
      float v1 = (lane < 3) ? (fj[64 + lane] + ci2) : -INFINITY;
      float bv_;
      int bi_;
      if (v1 > v0) { bv_ = v1; bi_ = 64 + lane; } else { bv_ = v0; bi_ = lane; }
#pragma unroll
      for (int o = 32; o > 0; o >>= 1) {
        float ov = __shfl_xor(bv_, o);
        int oi = __shfl_xor(bi_, o);
        if (ov > bv_ || (ov == bv_ && oi < bi_)) { bv_ = ov; bi_ = oi; }
      }
      jp[lane] = jpi;
      if (lane < 3) jp[64 + lane] = jpi2;
      LGKM_BARRIER();
      int s256 = (len > 256) ? jp[bi_] : 0;
      if (lane == 0) {
        ji[0] = bi_;
        ji[1] = s256;
      }
      __syncthreads();  // #2: junction published
      if (len > 256 && lane == 0) {
        int cur = ji[1];
        int p = 256;
        while (true) {
          out[p] = (float)cur;
          ++p;
          if (p >= len) break;
          cur = gp[(p - 256) * 68 + cur];
        }
      }
    }
  }
}

// ---------------- K3: den = lse(alpha+beta); loss = -sum(num-den)/B --------
__global__ __launch_bounds__(256) void k_final(const float* __restrict__ wsA,
                                               const float* __restrict__ wsB,
                                               const float* __restrict__ wsNum,
                                               float* __restrict__ out) {
  const int tid = threadIdx.x;
  const int w = tid >> 6, lane = tid & 63;
  float acc = 0.f;
  for (int s = w; s < NB; s += 4) {
    float v = wsA[s * 68 + lane] + wsB[s * 68 + lane];
    float v2 = (lane < 3) ? (wsA[s * 68 + 64 + lane] + wsB[s * 68 + 64 + lane])
                          : -INFINITY;
    float M = wave_max_dpp(fmaxf(v, v2));
    float e = __expf(v - M) + ((lane < 3) ? __expf(v2 - M) : 0.f);
    float den = M + __logf(wave_sum_dpp(e));
    acc += wsNum[s] - den;
  }
  __shared__ float part[4];
  if (lane == 0) part[w] = acc;
  __syncthreads();
  if (tid == 0) out[0] = -(part[0] + part[1] + part[2] + part[3]) / (float)NB;
}

extern "C" void kernel_launch(void* const* d_in, const int* in_sizes, int n_in,
                              void* d_out, int out_size, void* d_ws, size_t ws_size,
                              hipStream_t stream) {
  const float* hidden = (const float*)d_in[0];
  const float* W = (const float*)d_in[1];
  const float* bias = (const float*)d_in[2];
  const float* startv = (const float*)d_in[3];
  const float* endv = (const float*)d_in[4];
  const float* trans = (const float*)d_in[5];
  const int* labels = (const int*)d_in[6];
  const int* maskp = (const int*)d_in[7];
  float* out = (float*)d_out;

  float* scores = (float*)d_ws;  // 32*512*67 f32 = 4.39 MB
  float* wsA = scores + (size_t)NB * NL * NT;
  float* wsB = wsA + NB * 68;
  float* wsNum = wsB + NB * 68;

  hipLaunchKernelGGL(k_scores, dim3((NB * NL) / KR), dim3(256), 0, stream,
                     hidden, W, bias, scores);
  hipLaunchKernelGGL(k_scan, dim3(2 * NB), dim3(128), LDSV, stream,
                     scores, trans, startv, endv, labels, maskp,
                     wsA, wsB, wsNum, out + 1);
  hipLaunchKernelGGL(k_final, dim3(1), dim3(256), 0, stream,
                     wsA, wsB, wsNum, out);
}